// Round 6
// baseline (496.707 us; speedup 1.0000x reference)
//
#include <hip/hip_runtime.h>

// ---------------------------------------------------------------------------
// BitfieldLinear via rank-structure split:
//   y = r_n * P[m, c_n] + (a_m * s_n/127) * (xq @ qb^T) + bias
//   P = x @ basis^T  (bf16 MFMA, stored bf16 [M,256])
// R10: pre-kernel chain restructured. cvt_bf16 + quant_x + pack_q fused into
//      ONE multi-role prep kernel (concurrent memory streams, 5->3 launches).
//      gemm_i8 reverted to the R5-exact best-measured kernel (183.7 us);
//      p_gemm kept at R9 (512 thr, 2-deep prefetch).
// R11: fix R10's launch bug: n4p was N*K/16, must be N*K/4 (int4 = 4 int32
//      residuals -> one packed u32). 3/4 of Qb was garbage -> absmax 14.75.
// ---------------------------------------------------------------------------

typedef __bf16 bf16x8 __attribute__((ext_vector_type(8)));
typedef float f32x4 __attribute__((ext_vector_type(4)));
typedef int i32x4 __attribute__((ext_vector_type(4)));
typedef unsigned short u16x8 __attribute__((ext_vector_type(8)));

__device__ __forceinline__ unsigned short f2bf(float f) {
    union { float f; unsigned int u; } c; c.f = f;
    unsigned int u = c.u;
    u += 0x7fffu + ((u >> 16) & 1u);
    return (unsigned short)(u >> 16);
}
__device__ __forceinline__ float bf2f(unsigned short h) {
    union { unsigned int u; float f; } c; c.u = ((unsigned int)h) << 16;
    return c.f;
}

__device__ __forceinline__ void load_lds16(const void* g, void* l) {
    __builtin_amdgcn_global_load_lds(
        (__attribute__((address_space(1))) void*)(void*)g,
        (__attribute__((address_space(3))) void*)l,
        16, 0, 0);
}

// r4-verified swizzle for 64-B-row tiles (0 conflicts measured):
// physical 16B-slot p -> (row, chunk) byte offset; 8-slot groups span 2 rows.
__device__ __forceinline__ int swz_decode(int p, int row_bytes) {
    const int g = p >> 3, t = p & 7, v = t ^ (g & 7);
    const int row = g * 2 + (v >> 2), chunk = v & 3;
    return row * row_bytes + chunk * 16;
}

// ---------------- fused prep: cvt (basis->bf16) + quant_x + pack_q ---------
// Role by block id: [0,256) cvt; rest in groups of 3: {2 quant rows, 1 pack
// chunk}. Interleaving keeps all three DRAM streams in flight concurrently.
__global__ __launch_bounds__(256) void
prep_kernel(const float* __restrict__ x,        // [M,K] fp32
            signed char* __restrict__ xq,       // [M,K] i8 out
            float* __restrict__ arow,           // [M] out
            int M, int K,
            const int4* __restrict__ q4,        // residual int32, as int4
            unsigned int* __restrict__ qout,    // packed i8 out
            int n4p,
            const float4* __restrict__ b4,      // basis fp32, as float4
            ushort4* __restrict__ bb4,          // basis bf16 out
            int n4c) {
    const int id = blockIdx.x;
    const int tid = threadIdx.x;

    if (id < 256) {
        // ---- cvt role: 1024 float4 per block ----
#pragma unroll
        for (int k = 0; k < 4; ++k) {
            const int i = id * 1024 + k * 256 + tid;
            if (i < n4c) {
                float4 v = b4[i];
                ushort4 o;
                o.x = f2bf(v.x); o.y = f2bf(v.y);
                o.z = f2bf(v.z); o.w = f2bf(v.w);
                bb4[i] = o;
            }
        }
        return;
    }

    const int j = id - 256;
    const int g = j / 3;
    const int r = j - g * 3;

    if (r == 2) {
        // ---- pack role: 1024 int4 per block ----
#pragma unroll
        for (int k = 0; k < 4; ++k) {
            const int i = g * 1024 + k * 256 + tid;
            if (i < n4p) {
                int4 a = q4[i];
                unsigned int w = ((unsigned)(a.x - 128) & 0xFFu)
                               | (((unsigned)(a.y - 128) & 0xFFu) << 8)
                               | (((unsigned)(a.z - 128) & 0xFFu) << 16)
                               | (((unsigned)(a.w - 128) & 0xFFu) << 24);
                qout[i] = w;
            }
        }
        return;
    }

    // ---- quant role: one x row per block ----
    const int m = g * 2 + r;
    if (m >= M) return;
    const float* row = x + (size_t)m * K;
    const int base = tid * 16;
    float4 v[4];
#pragma unroll
    for (int jj = 0; jj < 4; ++jj) v[jj] = *(const float4*)(row + base + jj * 4);

    float lmax = 0.f;
#pragma unroll
    for (int jj = 0; jj < 4; ++jj) {
        lmax = fmaxf(lmax, fabsf(v[jj].x));
        lmax = fmaxf(lmax, fabsf(v[jj].y));
        lmax = fmaxf(lmax, fabsf(v[jj].z));
        lmax = fmaxf(lmax, fabsf(v[jj].w));
    }
#pragma unroll
    for (int off = 32; off; off >>= 1)
        lmax = fmaxf(lmax, __shfl_xor(lmax, off));
    __shared__ float smax[4];
    if ((tid & 63) == 0) smax[tid >> 6] = lmax;
    __syncthreads();
    const float mx = fmaxf(fmaxf(smax[0], smax[1]), fmaxf(smax[2], smax[3]));
    const float inv = mx > 0.f ? 127.0f / mx : 0.0f;
    if (tid == 0) arow[m] = mx * (1.0f / 127.0f);

    union { signed char c[16]; i32x4 w; } pk;
#pragma unroll
    for (int jj = 0; jj < 4; ++jj) {
        pk.c[jj * 4 + 0] = (signed char)(int)rintf(v[jj].x * inv);
        pk.c[jj * 4 + 1] = (signed char)(int)rintf(v[jj].y * inv);
        pk.c[jj * 4 + 2] = (signed char)(int)rintf(v[jj].z * inv);
        pk.c[jj * 4 + 3] = (signed char)(int)rintf(v[jj].w * inv);
    }
    *(i32x4*)(xq + (size_t)m * K + base) = pk.w;
}

// ---------------- P = x @ basis^T, bf16 out --------------------------------
// Tile: 32 rows (M) x 256 cols (ALL of basis), BK=64. 256 blocks (M/32).
// 512 threads (8 waves, wave = 16 rows x 64 cols), double-buffered
// staging with counted vmcnt(5) so next tile's HBM latency hides under MFMA.
__global__ __launch_bounds__(512) void
p_gemm_kernel(const float* __restrict__ x,           // [M,K] fp32
              const unsigned short* __restrict__ Bb, // [256,K] bf16
              unsigned short* __restrict__ Pbf,      // [M,256] bf16
              int M, int K) {
    __shared__ __align__(16) float As[2][32 * 64];            // 2 x 8 KB
    __shared__ __align__(16) unsigned short Bs[2][256 * 64];  // 2 x 32 KB

    const int tid  = threadIdx.x;
    const int lane = tid & 63;
    const int wv   = tid >> 6;        // 0..7
    const int wr   = wv >> 2;         // 0..1: row half (16 rows)
    const int wc   = wv & 3;          // 0..3: 64-col group
    const int m0 = blockIdx.x * 32;
    const int lr = lane & 15;
    const int kg = lane >> 4;

    f32x4 acc[4];
#pragma unroll
    for (int ni = 0; ni < 4; ++ni) acc[ni] = (f32x4){0.f, 0.f, 0.f, 0.f};

    // A staging: 512 slots (32 rows x 16 chunks of 4 fp32), 1/thread.
    const int aRow = tid >> 4;
    const int aSrc = (tid & 15) ^ (aRow & 15);
    // B staging: 2048 slots (256 rows x 8 chunks of 8 bf16), 4/thread.
    int bRow[4], bSrc[4];
#pragma unroll
    for (int j = 0; j < 4; ++j) {
        const int p = tid + 512 * j;
        bRow[j] = p >> 3;
        bSrc[j] = (p & 7) ^ (bRow[j] & 7);
    }
    const float* aG = x + (size_t)(m0 + aRow) * K + aSrc * 4;
    const unsigned short* bG[4];
#pragma unroll
    for (int j = 0; j < 4; ++j) bG[j] = Bb + (size_t)bRow[j] * K + bSrc[j] * 8;

#define P_STAGE(bb, k0)                                                        \
    do {                                                                       \
        load_lds16(aG + (k0), (char*)As[bb] + tid * 16);                       \
        _Pragma("unroll") for (int j = 0; j < 4; ++j)                          \
            load_lds16(bG[j] + (k0), (char*)Bs[bb] + (tid + 512 * j) * 16);    \
    } while (0)

    P_STAGE(0, 0);
    const int NT = K >> 6;
    for (int t = 0; t < NT; ++t) {
        const int bb = t & 1;
        if (t + 1 < NT) {
            P_STAGE(bb ^ 1, (t + 1) << 6);
            asm volatile("s_waitcnt vmcnt(5)" ::: "memory");  // tile t resident
        } else {
            asm volatile("s_waitcnt vmcnt(0)" ::: "memory");
        }
        __builtin_amdgcn_s_barrier();

        const float* Ab = As[bb];
        const unsigned short* Bbf = Bs[bb];
#pragma unroll
        for (int s = 0; s < 2; ++s) {
            const int r = wr * 16 + lr;
            const int c0 = s * 8 + kg * 2;
            const int ph0 = c0 ^ (r & 15);
            const int ph1 = (c0 + 1) ^ (r & 15);
            f32x4 lo = *(const f32x4*)(Ab + r * 64 + ph0 * 4);
            f32x4 hi = *(const f32x4*)(Ab + r * 64 + ph1 * 4);
            bf16x8 a;
            a[0] = (__bf16)lo[0]; a[1] = (__bf16)lo[1];
            a[2] = (__bf16)lo[2]; a[3] = (__bf16)lo[3];
            a[4] = (__bf16)hi[0]; a[5] = (__bf16)hi[1];
            a[6] = (__bf16)hi[2]; a[7] = (__bf16)hi[3];
#pragma unroll
            for (int ni = 0; ni < 4; ++ni) {
                const int rb = wc * 64 + ni * 16 + lr;
                const int ph = (s * 4 + kg) ^ (rb & 7);
                bf16x8 bfr = __builtin_bit_cast(bf16x8,
                    *(const u16x8*)(Bbf + rb * 64 + ph * 8));
                acc[ni] = __builtin_amdgcn_mfma_f32_16x16x32_bf16(
                    a, bfr, acc[ni], 0, 0, 0);
            }
        }
        __builtin_amdgcn_s_barrier();
    }
#undef P_STAGE

#pragma unroll
    for (int ni = 0; ni < 4; ++ni) {
        const int n = wc * 64 + ni * 16 + lr;
        const int mb = m0 + wr * 16 + kg * 4;
#pragma unroll
        for (int rg = 0; rg < 4; ++rg)
            Pbf[(size_t)(mb + rg) * 256 + n] = f2bf(acc[ni][rg]);
    }
}

// ---------------- main i8 GEMM + fused epilogue (R5-exact) -----------------
// 128(M) x 256(N) tile, BK=64. 4 waves 2x2; wave = 64 rows x 128 cols
// (af[4], bfr[8], acc[4][8]). Swizzled LDS, epilogue P gather, NT stores.
__global__ __launch_bounds__(256, 2) void
gemm_i8_kernel(const signed char* __restrict__ Xq, // [M,K]
               const signed char* __restrict__ Qb, // [N,K]
               const float* __restrict__ arow,     // [M]
               const int* __restrict__ codes,      // [N]
               const float* __restrict__ scales,   // [N]
               const float* __restrict__ bias,     // [N]
               const unsigned short* __restrict__ Pbf, // [M,256] bf16
               float* __restrict__ out,            // [M,N]
               int M, int N, int K) {
    __shared__ __align__(16) signed char As[128 * 64];  //  8 KB
    __shared__ __align__(16) signed char Bs[256 * 64];  // 16 KB

    const int tid  = threadIdx.x;
    const int lane = tid & 63;
    const int wv   = tid >> 6;
    const int wr   = wv >> 1;         // 0..1 (row half)
    const int wc   = wv & 1;          // 0..1 (col half)
    const int m0 = blockIdx.x * 128;  // m-major grid: consecutive blocks share n0
    const int n0 = blockIdx.y * 256;
    const int lr = lane & 15;
    const int kg = lane >> 4;
    const int cidx = (((lr & 1) << 2) | kg) ^ ((lr >> 1) & 7);

    i32x4 acc[4][8];
#pragma unroll
    for (int mi = 0; mi < 4; ++mi)
#pragma unroll
        for (int ni = 0; ni < 8; ++ni)
            acc[mi][ni] = (i32x4){0, 0, 0, 0};

    // A: 512 slots (2/thread); B: 1024 slots (4/thread). 64-B rows, r4 swizzle.
    int gaOff[2], gbOff[4];
#pragma unroll
    for (int j = 0; j < 2; ++j) gaOff[j] = swz_decode(tid + 256 * j, 64);
#pragma unroll
    for (int j = 0; j < 4; ++j) gbOff[j] = swz_decode(tid + 256 * j, 64);

    for (int k0 = 0; k0 < K; k0 += 64) {
#pragma unroll
        for (int j = 0; j < 2; ++j)
            load_lds16(Xq + (size_t)(m0 + (gaOff[j] >> 6)) * K + (gaOff[j] & 63) + k0,
                       As + (tid + 256 * j) * 16);
#pragma unroll
        for (int j = 0; j < 4; ++j)
            load_lds16(Qb + (size_t)(n0 + (gbOff[j] >> 6)) * K + (gbOff[j] & 63) + k0,
                       Bs + (tid + 256 * j) * 16);
        __syncthreads();

        i32x4 af[4], bfr[8];
#pragma unroll
        for (int mi = 0; mi < 4; ++mi) {
            const int r2 = wr * 32 + mi * 8 + (lr >> 1);
            af[mi] = *(const i32x4*)(As + r2 * 128 + cidx * 16);
        }
#pragma unroll
        for (int ni = 0; ni < 8; ++ni) {
            const int r2 = wc * 64 + ni * 8 + (lr >> 1);
            bfr[ni] = *(const i32x4*)(Bs + r2 * 128 + cidx * 16);
        }
#pragma unroll
        for (int mi = 0; mi < 4; ++mi)
#pragma unroll
            for (int ni = 0; ni < 8; ++ni)
                acc[mi][ni] = __builtin_amdgcn_mfma_i32_16x16x64_i8(
                    af[mi], bfr[ni], acc[mi][ni], 0, 0, 0);
        __syncthreads();
    }

    // ---- epilogue: per-row x scales, per-col decode, P gather, NT store ---
    float av[4][4];
#pragma unroll
    for (int mi = 0; mi < 4; ++mi)
#pragma unroll
        for (int rg = 0; rg < 4; ++rg)
            av[mi][rg] = arow[m0 + wr * 64 + mi * 16 + kg * 4 + rg];

#pragma unroll
    for (int ni = 0; ni < 8; ++ni) {
        const int n = n0 + wc * 128 + ni * 16 + lr;
        const int code = codes[n];
        const int cc = code & 0xFF;
        const float rr = (float)((code >> 8) & 0xFFFF) * (1.0f / 65535.0f);
        const float so = scales[n] * (1.0f / 127.0f);
        const float bv = bias[n];
#pragma unroll
        for (int mi = 0; mi < 4; ++mi) {
            const int mbase = m0 + wr * 64 + mi * 16 + kg * 4;
            unsigned short pv[4];
#pragma unroll
            for (int rg = 0; rg < 4; ++rg)
                pv[rg] = Pbf[(size_t)(mbase + rg) * 256 + cc];
#pragma unroll
            for (int rg = 0; rg < 4; ++rg) {
                const float y = av[mi][rg] * so * (float)acc[mi][ni][rg]
                              + rr * bf2f(pv[rg]) + bv;
                __builtin_nontemporal_store(y, &out[(size_t)(mbase + rg) * N + n]);
            }
        }
    }
}

// ---------------------------------------------------------------------------
extern "C" void kernel_launch(void* const* d_in, const int* in_sizes, int n_in,
                              void* d_out, int out_size, void* d_ws, size_t ws_size,
                              hipStream_t stream) {
    const float* x        = (const float*)d_in[0];
    const int*   codes    = (const int*)d_in[1];
    const float* basis    = (const float*)d_in[2];
    const int*   q        = (const int*)d_in[3];
    const float* scales   = (const float*)d_in[4];
    const float* bias     = (const float*)d_in[5];
    float* out = (float*)d_out;

    const int BASIS = 256;
    const int K = in_sizes[2] / BASIS;   // 4096
    const int N = in_sizes[1];           // 4096
    const int M = in_sizes[0] / K;       // 8192

    char* ws = (char*)d_ws;
    signed char* Xq = (signed char*)ws;                  // [M,K] i8, 33.5 MB
    size_t off = (size_t)M * K;
    signed char* Qb = (signed char*)(ws + off);          // [N,K] i8, 16.7 MB
    off += (size_t)N * K;
    unsigned short* Pbf = (unsigned short*)(ws + off);   // [M,256] bf16, 4 MB
    off += (size_t)M * 256 * 2;
    float* Arow = (float*)(ws + off);                    // [M] fp32
    off += (size_t)M * sizeof(float);
    unsigned short* Bb = (unsigned short*)(ws + off);    // [256,K] bf16, 2 MB

    const int n4p = N * K / 4;           // int4 chunks of residual (4 i32 each)
    const int n4c = BASIS * K / 4;       // float4 chunks of basis
    const int g_quant = (M + 1) / 2;
    const int g_pack  = (n4p + 1023) / 1024;
    const int G3 = g_quant > g_pack ? g_quant : g_pack;
    const int NB = 256 + 3 * G3;

    // 1. fused prep: basis->bf16  ||  x->i8 + row scale  ||  residual->i8
    prep_kernel<<<NB, 256, 0, stream>>>(x, Xq, Arow, M, K,
                                        (const int4*)q, (unsigned int*)Qb, n4p,
                                        (const float4*)basis, (ushort4*)Bb, n4c);
    // 2. P = x @ basis^T  (reads x fp32 directly)
    p_gemm_kernel<<<M / 32, 512, 0, stream>>>(x, Bb, Pbf, M, K);
    // 3. main GEMM + fused epilogue
    gemm_i8_kernel<<<dim3(M / 128, N / 256), 256, 0, stream>>>(
        Xq, Qb, Arow, codes, scales, bias, Pbf, out, M, N, K);
}

// Round 7
// 493.403 us; speedup vs baseline: 1.0067x; 1.0067x over previous
//
#include <hip/hip_runtime.h>

// ---------------------------------------------------------------------------
// BitfieldLinear via rank-structure split:
//   y = r_n * P[m, c_n] + (a_m * s_n/127) * (xq @ qb^T) + bias
//   P = x @ basis^T  (bf16 MFMA, stored bf16 [M,256])
// R12: p_gemm restructured from 1 block/CU (256 blocks, stall-exposed) to
//      2 blocks/CU: tile 32x128 (half of basis), grid (2, M/32)=512 blocks,
//      256 thr / 4 waves, 48 KB LDS, R9-verified dbuf + vmcnt(6).
//      prep = R11-exact; gemm_i8 = R5-exact (182 us measured).
// ---------------------------------------------------------------------------

typedef __bf16 bf16x8 __attribute__((ext_vector_type(8)));
typedef float f32x4 __attribute__((ext_vector_type(4)));
typedef int i32x4 __attribute__((ext_vector_type(4)));
typedef unsigned short u16x8 __attribute__((ext_vector_type(8)));

__device__ __forceinline__ unsigned short f2bf(float f) {
    union { float f; unsigned int u; } c; c.f = f;
    unsigned int u = c.u;
    u += 0x7fffu + ((u >> 16) & 1u);
    return (unsigned short)(u >> 16);
}
__device__ __forceinline__ float bf2f(unsigned short h) {
    union { unsigned int u; float f; } c; c.u = ((unsigned int)h) << 16;
    return c.f;
}

__device__ __forceinline__ void load_lds16(const void* g, void* l) {
    __builtin_amdgcn_global_load_lds(
        (__attribute__((address_space(1))) void*)(void*)g,
        (__attribute__((address_space(3))) void*)l,
        16, 0, 0);
}

// r4-verified swizzle for 64-B-row tiles (0 conflicts measured):
// physical 16B-slot p -> (row, chunk) byte offset; 8-slot groups span 2 rows.
__device__ __forceinline__ int swz_decode(int p, int row_bytes) {
    const int g = p >> 3, t = p & 7, v = t ^ (g & 7);
    const int row = g * 2 + (v >> 2), chunk = v & 3;
    return row * row_bytes + chunk * 16;
}

// ---------------- fused prep: cvt (basis->bf16) + quant_x + pack_q ---------
// Role by block id: [0,256) cvt; rest in groups of 3: {2 quant rows, 1 pack
// chunk}. Interleaving keeps all three DRAM streams in flight concurrently.
__global__ __launch_bounds__(256) void
prep_kernel(const float* __restrict__ x,        // [M,K] fp32
            signed char* __restrict__ xq,       // [M,K] i8 out
            float* __restrict__ arow,           // [M] out
            int M, int K,
            const int4* __restrict__ q4,        // residual int32, as int4
            unsigned int* __restrict__ qout,    // packed i8 out
            int n4p,
            const float4* __restrict__ b4,      // basis fp32, as float4
            ushort4* __restrict__ bb4,          // basis bf16 out
            int n4c) {
    const int id = blockIdx.x;
    const int tid = threadIdx.x;

    if (id < 256) {
        // ---- cvt role: 1024 float4 per block ----
#pragma unroll
        for (int k = 0; k < 4; ++k) {
            const int i = id * 1024 + k * 256 + tid;
            if (i < n4c) {
                float4 v = b4[i];
                ushort4 o;
                o.x = f2bf(v.x); o.y = f2bf(v.y);
                o.z = f2bf(v.z); o.w = f2bf(v.w);
                bb4[i] = o;
            }
        }
        return;
    }

    const int j = id - 256;
    const int g = j / 3;
    const int r = j - g * 3;

    if (r == 2) {
        // ---- pack role: 1024 int4 per block ----
#pragma unroll
        for (int k = 0; k < 4; ++k) {
            const int i = g * 1024 + k * 256 + tid;
            if (i < n4p) {
                int4 a = q4[i];
                unsigned int w = ((unsigned)(a.x - 128) & 0xFFu)
                               | (((unsigned)(a.y - 128) & 0xFFu) << 8)
                               | (((unsigned)(a.z - 128) & 0xFFu) << 16)
                               | (((unsigned)(a.w - 128) & 0xFFu) << 24);
                qout[i] = w;
            }
        }
        return;
    }

    // ---- quant role: one x row per block ----
    const int m = g * 2 + r;
    if (m >= M) return;
    const float* row = x + (size_t)m * K;
    const int base = tid * 16;
    float4 v[4];
#pragma unroll
    for (int jj = 0; jj < 4; ++jj) v[jj] = *(const float4*)(row + base + jj * 4);

    float lmax = 0.f;
#pragma unroll
    for (int jj = 0; jj < 4; ++jj) {
        lmax = fmaxf(lmax, fabsf(v[jj].x));
        lmax = fmaxf(lmax, fabsf(v[jj].y));
        lmax = fmaxf(lmax, fabsf(v[jj].z));
        lmax = fmaxf(lmax, fabsf(v[jj].w));
    }
#pragma unroll
    for (int off = 32; off; off >>= 1)
        lmax = fmaxf(lmax, __shfl_xor(lmax, off));
    __shared__ float smax[4];
    if ((tid & 63) == 0) smax[tid >> 6] = lmax;
    __syncthreads();
    const float mx = fmaxf(fmaxf(smax[0], smax[1]), fmaxf(smax[2], smax[3]));
    const float inv = mx > 0.f ? 127.0f / mx : 0.0f;
    if (tid == 0) arow[m] = mx * (1.0f / 127.0f);

    union { signed char c[16]; i32x4 w; } pk;
#pragma unroll
    for (int jj = 0; jj < 4; ++jj) {
        pk.c[jj * 4 + 0] = (signed char)(int)rintf(v[jj].x * inv);
        pk.c[jj * 4 + 1] = (signed char)(int)rintf(v[jj].y * inv);
        pk.c[jj * 4 + 2] = (signed char)(int)rintf(v[jj].z * inv);
        pk.c[jj * 4 + 3] = (signed char)(int)rintf(v[jj].w * inv);
    }
    *(i32x4*)(xq + (size_t)m * K + base) = pk.w;
}

// ---------------- P = x @ basis^T, bf16 out --------------------------------
// R12: tile 32 rows (M) x 128 cols (basis half), BK=64. Grid (2, M/32) = 512
// blocks -> 2 blocks/CU (48 KB LDS each). 256 thr / 4 waves (2 row-halves x
// 2 col-halves, wave = 16 rows x 64 cols). R9-verified dbuf staging with
// counted vmcnt(6): 6 loads/tile, 12 outstanding at wait.
__global__ __launch_bounds__(256) void
p_gemm_kernel(const float* __restrict__ x,           // [M,K] fp32
              const unsigned short* __restrict__ Bb, // [256,K] bf16
              unsigned short* __restrict__ Pbf,      // [M,256] bf16
              int M, int K) {
    __shared__ __align__(16) float As[2][32 * 64];            // 2 x 8 KB
    __shared__ __align__(16) unsigned short Bs[2][128 * 64];  // 2 x 16 KB

    const int tid  = threadIdx.x;
    const int lane = tid & 63;
    const int wv   = tid >> 6;        // 0..3
    const int wr   = wv >> 1;         // 0..1: row half (16 rows)
    const int wc   = wv & 1;          // 0..1: 64-col half
    const int nh   = blockIdx.x;      // 0..1: which 128 basis rows
    const int m0   = blockIdx.y * 32;
    const int lr = lane & 15;
    const int kg = lane >> 4;

    f32x4 acc[4];
#pragma unroll
    for (int ni = 0; ni < 4; ++ni) acc[ni] = (f32x4){0.f, 0.f, 0.f, 0.f};

    // A staging: 512 slots (32 rows x 16 chunks of 4 fp32), 2/thread.
    int aRow[2], aSrc[2];
#pragma unroll
    for (int j = 0; j < 2; ++j) {
        const int p = tid + 256 * j;
        aRow[j] = p >> 4;
        aSrc[j] = (p & 15) ^ (aRow[j] & 15);
    }
    // B staging: 1024 slots (128 rows x 8 chunks of 8 bf16), 4/thread.
    int bRow[4], bSrc[4];
#pragma unroll
    for (int j = 0; j < 4; ++j) {
        const int p = tid + 256 * j;
        bRow[j] = p >> 3;
        bSrc[j] = (p & 7) ^ (bRow[j] & 7);
    }
    const float* aG[2];
#pragma unroll
    for (int j = 0; j < 2; ++j)
        aG[j] = x + (size_t)(m0 + aRow[j]) * K + aSrc[j] * 4;
    const unsigned short* bG[4];
#pragma unroll
    for (int j = 0; j < 4; ++j)
        bG[j] = Bb + (size_t)(nh * 128 + bRow[j]) * K + bSrc[j] * 8;

#define P_STAGE(bb, k0)                                                        \
    do {                                                                       \
        _Pragma("unroll") for (int j = 0; j < 2; ++j)                          \
            load_lds16(aG[j] + (k0), (char*)As[bb] + (tid + 256 * j) * 16);    \
        _Pragma("unroll") for (int j = 0; j < 4; ++j)                          \
            load_lds16(bG[j] + (k0), (char*)Bs[bb] + (tid + 256 * j) * 16);    \
    } while (0)

    P_STAGE(0, 0);
    const int NT = K >> 6;
    for (int t = 0; t < NT; ++t) {
        const int bb = t & 1;
        if (t + 1 < NT) {
            P_STAGE(bb ^ 1, (t + 1) << 6);
            asm volatile("s_waitcnt vmcnt(6)" ::: "memory");  // tile t resident
        } else {
            asm volatile("s_waitcnt vmcnt(0)" ::: "memory");
        }
        __builtin_amdgcn_s_barrier();

        const float* Ab = As[bb];
        const unsigned short* Bbf = Bs[bb];
#pragma unroll
        for (int s = 0; s < 2; ++s) {
            const int r = wr * 16 + lr;
            const int c0 = s * 8 + kg * 2;
            const int ph0 = c0 ^ (r & 15);
            const int ph1 = (c0 + 1) ^ (r & 15);
            f32x4 lo = *(const f32x4*)(Ab + r * 64 + ph0 * 4);
            f32x4 hi = *(const f32x4*)(Ab + r * 64 + ph1 * 4);
            bf16x8 a;
            a[0] = (__bf16)lo[0]; a[1] = (__bf16)lo[1];
            a[2] = (__bf16)lo[2]; a[3] = (__bf16)lo[3];
            a[4] = (__bf16)hi[0]; a[5] = (__bf16)hi[1];
            a[6] = (__bf16)hi[2]; a[7] = (__bf16)hi[3];
#pragma unroll
            for (int ni = 0; ni < 4; ++ni) {
                const int rb = wc * 64 + ni * 16 + lr;
                const int ph = (s * 4 + kg) ^ (rb & 7);
                bf16x8 bfr = __builtin_bit_cast(bf16x8,
                    *(const u16x8*)(Bbf + rb * 64 + ph * 8));
                acc[ni] = __builtin_amdgcn_mfma_f32_16x16x32_bf16(
                    a, bfr, acc[ni], 0, 0, 0);
            }
        }
        __builtin_amdgcn_s_barrier();
    }
#undef P_STAGE

#pragma unroll
    for (int ni = 0; ni < 4; ++ni) {
        const int n = nh * 128 + wc * 64 + ni * 16 + lr;
        const int mb = m0 + wr * 16 + kg * 4;
#pragma unroll
        for (int rg = 0; rg < 4; ++rg)
            Pbf[(size_t)(mb + rg) * 256 + n] = f2bf(acc[ni][rg]);
    }
}

// ---------------- main i8 GEMM + fused epilogue (R5-exact) -----------------
// 128(M) x 256(N) tile, BK=64. 4 waves 2x2; wave = 64 rows x 128 cols
// (af[4], bfr[8], acc[4][8]). Swizzled LDS, epilogue P gather, NT stores.
__global__ __launch_bounds__(256, 2) void
gemm_i8_kernel(const signed char* __restrict__ Xq, // [M,K]
               const signed char* __restrict__ Qb, // [N,K]
               const float* __restrict__ arow,     // [M]
               const int* __restrict__ codes,      // [N]
               const float* __restrict__ scales,   // [N]
               const float* __restrict__ bias,     // [N]
               const unsigned short* __restrict__ Pbf, // [M,256] bf16
               float* __restrict__ out,            // [M,N]
               int M, int N, int K) {
    __shared__ __align__(16) signed char As[128 * 64];  //  8 KB
    __shared__ __align__(16) signed char Bs[256 * 64];  // 16 KB

    const int tid  = threadIdx.x;
    const int lane = tid & 63;
    const int wv   = tid >> 6;
    const int wr   = wv >> 1;         // 0..1 (row half)
    const int wc   = wv & 1;          // 0..1 (col half)
    const int m0 = blockIdx.x * 128;  // m-major grid: consecutive blocks share n0
    const int n0 = blockIdx.y * 256;
    const int lr = lane & 15;
    const int kg = lane >> 4;
    const int cidx = (((lr & 1) << 2) | kg) ^ ((lr >> 1) & 7);

    i32x4 acc[4][8];
#pragma unroll
    for (int mi = 0; mi < 4; ++mi)
#pragma unroll
        for (int ni = 0; ni < 8; ++ni)
            acc[mi][ni] = (i32x4){0, 0, 0, 0};

    // A: 512 slots (2/thread); B: 1024 slots (4/thread). 64-B rows, r4 swizzle.
    int gaOff[2], gbOff[4];
#pragma unroll
    for (int j = 0; j < 2; ++j) gaOff[j] = swz_decode(tid + 256 * j, 64);
#pragma unroll
    for (int j = 0; j < 4; ++j) gbOff[j] = swz_decode(tid + 256 * j, 64);

    for (int k0 = 0; k0 < K; k0 += 64) {
#pragma unroll
        for (int j = 0; j < 2; ++j)
            load_lds16(Xq + (size_t)(m0 + (gaOff[j] >> 6)) * K + (gaOff[j] & 63) + k0,
                       As + (tid + 256 * j) * 16);
#pragma unroll
        for (int j = 0; j < 4; ++j)
            load_lds16(Qb + (size_t)(n0 + (gbOff[j] >> 6)) * K + (gbOff[j] & 63) + k0,
                       Bs + (tid + 256 * j) * 16);
        __syncthreads();

        i32x4 af[4], bfr[8];
#pragma unroll
        for (int mi = 0; mi < 4; ++mi) {
            const int r2 = wr * 32 + mi * 8 + (lr >> 1);
            af[mi] = *(const i32x4*)(As + r2 * 128 + cidx * 16);
        }
#pragma unroll
        for (int ni = 0; ni < 8; ++ni) {
            const int r2 = wc * 64 + ni * 8 + (lr >> 1);
            bfr[ni] = *(const i32x4*)(Bs + r2 * 128 + cidx * 16);
        }
#pragma unroll
        for (int mi = 0; mi < 4; ++mi)
#pragma unroll
            for (int ni = 0; ni < 8; ++ni)
                acc[mi][ni] = __builtin_amdgcn_mfma_i32_16x16x64_i8(
                    af[mi], bfr[ni], acc[mi][ni], 0, 0, 0);
        __syncthreads();
    }

    // ---- epilogue: per-row x scales, per-col decode, P gather, NT store ---
    float av[4][4];
#pragma unroll
    for (int mi = 0; mi < 4; ++mi)
#pragma unroll
        for (int rg = 0; rg < 4; ++rg)
            av[mi][rg] = arow[m0 + wr * 64 + mi * 16 + kg * 4 + rg];

#pragma unroll
    for (int ni = 0; ni < 8; ++ni) {
        const int n = n0 + wc * 128 + ni * 16 + lr;
        const int code = codes[n];
        const int cc = code & 0xFF;
        const float rr = (float)((code >> 8) & 0xFFFF) * (1.0f / 65535.0f);
        const float so = scales[n] * (1.0f / 127.0f);
        const float bv = bias[n];
#pragma unroll
        for (int mi = 0; mi < 4; ++mi) {
            const int mbase = m0 + wr * 64 + mi * 16 + kg * 4;
            unsigned short pv[4];
#pragma unroll
            for (int rg = 0; rg < 4; ++rg)
                pv[rg] = Pbf[(size_t)(mbase + rg) * 256 + cc];
#pragma unroll
            for (int rg = 0; rg < 4; ++rg) {
                const float y = av[mi][rg] * so * (float)acc[mi][ni][rg]
                              + rr * bf2f(pv[rg]) + bv;
                __builtin_nontemporal_store(y, &out[(size_t)(mbase + rg) * N + n]);
            }
        }
    }
}

// ---------------------------------------------------------------------------
extern "C" void kernel_launch(void* const* d_in, const int* in_sizes, int n_in,
                              void* d_out, int out_size, void* d_ws, size_t ws_size,
                              hipStream_t stream) {
    const float* x        = (const float*)d_in[0];
    const int*   codes    = (const int*)d_in[1];
    const float* basis    = (const float*)d_in[2];
    const int*   q        = (const int*)d_in[3];
    const float* scales   = (const float*)d_in[4];
    const float* bias     = (const float*)d_in[5];
    float* out = (float*)d_out;

    const int BASIS = 256;
    const int K = in_sizes[2] / BASIS;   // 4096
    const int N = in_sizes[1];           // 4096
    const int M = in_sizes[0] / K;       // 8192

    char* ws = (char*)d_ws;
    signed char* Xq = (signed char*)ws;                  // [M,K] i8, 33.5 MB
    size_t off = (size_t)M * K;
    signed char* Qb = (signed char*)(ws + off);          // [N,K] i8, 16.7 MB
    off += (size_t)N * K;
    unsigned short* Pbf = (unsigned short*)(ws + off);   // [M,256] bf16, 4 MB
    off += (size_t)M * 256 * 2;
    float* Arow = (float*)(ws + off);                    // [M] fp32
    off += (size_t)M * sizeof(float);
    unsigned short* Bb = (unsigned short*)(ws + off);    // [256,K] bf16, 2 MB

    const int n4p = N * K / 4;           // int4 chunks of residual (4 i32 each)
    const int n4c = BASIS * K / 4;       // float4 chunks of basis
    const int g_quant = (M + 1) / 2;
    const int g_pack  = (n4p + 1023) / 1024;
    const int G3 = g_quant > g_pack ? g_quant : g_pack;
    const int NB = 256 + 3 * G3;

    // 1. fused prep: basis->bf16  ||  x->i8 + row scale  ||  residual->i8
    prep_kernel<<<NB, 256, 0, stream>>>(x, Xq, Arow, M, K,
                                        (const int4*)q, (unsigned int*)Qb, n4p,
                                        (const float4*)basis, (ushort4*)Bb, n4c);
    // 2. P = x @ basis^T  (2 blocks/CU, counted-vmcnt dbuf)
    p_gemm_kernel<<<dim3(2, M / 32), 256, 0, stream>>>(x, Bb, Pbf, M, K);
    // 3. main GEMM + fused epilogue
    gemm_i8_kernel<<<dim3(M / 128, N / 256), 256, 0, stream>>>(
        Xq, Qb, Arow, codes, scales, bias, Pbf, out, M, N, K);
}